// Round 1
// 162.867 us; speedup vs baseline: 1.1043x; 1.1043x over previous
//
#include <hip/hip_runtime.h>
#include <stdint.h>

// Problem constants (fixed by the reference)
#define BQ   2
#define NQ   8192
#define D1Q  128
#define D2Q  256
#define OUTQ 128
#define CATQ 384   // D1+D2
#define KQ   16

// bf16 split helpers (RNE)
__device__ __forceinline__ ushort f2bf(float f) {
    uint32_t u = __float_as_uint(f);
    return (ushort)((u + 0x7FFFu + ((u >> 16) & 1u)) >> 16);
}
__device__ __forceinline__ float bf2f(ushort h) {
    return __uint_as_float((uint32_t)h << 16);
}

typedef __attribute__((ext_vector_type(8))) short short8v;   // 8 bf16 (4 VGPRs)
typedef __attribute__((ext_vector_type(4))) float f32x4v;    // MFMA accumulator

// ---------------------------------------------------------------------------
// Kernel 1: prep = W split to bf16 hi/lo in MFMA B-fragment layout + xyz1 norms.
// B-fragment layout for mfma_f32_16x16x32_bf16:
//   flat = ((kt*8 + ct)*64 + lane)*8 + r
//   col o = ct*16 + (lane&15);  k = kt*32 + (lane>>4)*8 + r
// ---------------------------------------------------------------------------
__global__ void prep_kernel(const float* __restrict__ W,
                            ushort* __restrict__ Wfh, ushort* __restrict__ Wfl,
                            const float* __restrict__ xyz1,
                            float4* __restrict__ xyz1n) {
    int flat = blockIdx.x * 256 + threadIdx.x;
    if (flat < CATQ * OUTQ) {
        int r    = flat & 7;
        int lane = (flat >> 3) & 63;
        int ctk  = flat >> 9;
        int ct   = ctk & 7;
        int kt   = ctk >> 3;
        int o = ct * 16 + (lane & 15);
        int k = kt * 32 + (lane >> 4) * 8 + r;
        float v  = W[o * CATQ + k];
        ushort h = f2bf(v);
        Wfh[flat] = h;
        Wfl[flat] = f2bf(v - bf2f(h));
    }
    if (flat < BQ * NQ) {
        float x = xyz1[flat * 3 + 0];
        float y = xyz1[flat * 3 + 1];
        float z = xyz1[flat * 3 + 2];
        float n;
        {
            #pragma clang fp contract(off)
            float px = x * x, py = y * y, pz = z * z;
            n = (px + py) + pz;
        }
        xyz1n[flat] = make_float4(x, y, z, n);
    }
}

__device__ __forceinline__ void fma4(float4& acc, float a, const float4& w) {
    acc.x = fmaf(a, w.x, acc.x);
    acc.y = fmaf(a, w.y, acc.y);
    acc.z = fmaf(a, w.z, acc.z);
    acc.w = fmaf(a, w.w, acc.w);
}

// numpy-exact squared distance (same rounding as the reference BLAS path)
__device__ __forceinline__ float npy_d2(float4 pt, float qx, float qy, float qz,
                                        float s2) {
    #pragma clang fp contract(off)
    float d0  = pt.x * qx;                 // rounded product
    float dot = fmaf(pt.y, qy, d0);        // explicit FMA chain
    dot       = fmaf(pt.z, qz, dot);
    float tt  = s2 + pt.w;                 // rounded add
    return tt - 2.0f * dot;                // 2*dot exact; rounded sub
}

// 4-op reduced proxy: exact_d2 ~= s2 + red within ~1.5e-5 (values O(30)).
// Phase-1 bound only; never used for keys.
__device__ __forceinline__ float red_r(float4 pt, float qx, float qy, float qz) {
    float dot = fmaf(pt.z, qz, fmaf(pt.y, qy, pt.x * qx));
    return fmaf(-2.0f, dot, pt.w);
}
#define RED_MARGIN 1e-3f   // >= 60x the proxy-vs-exact bound

// full ascending bitonic sort of one uint64 per lane across the wave
__device__ __forceinline__ uint64_t sort64(uint64_t x, int lane) {
    #pragma unroll
    for (int k = 2; k <= 64; k <<= 1) {
        #pragma unroll
        for (int j = k >> 1; j > 0; j >>= 1) {
            uint64_t p = __shfl_xor((unsigned long long)x, j, 64);
            bool keep_min = (((lane & j) == 0) == ((lane & k) == 0));
            bool pless    = p < x;
            x = (pless == keep_min) ? p : x;   // ties: same value either way
        }
    }
    return x;
}

// ---------------------------------------------------------------------------
// Kernel 2 (R14): fused NN + interp + MFMA GEMM. Per block: 16 queries.
// Changes vs R13 (counters: MfmaUtil 0, VALUBusy 61% -> stage-3 scalar GEMM
// was ~1/3 of VALU):
//  - Stage 3 is now mfma_f32_16x16x32_bf16 with a 3-term bf16 split
//    (hi*hi + lo*hi + hi*lo); rel err ~2^-17 per term, well under tolerance.
//  - W is pre-split + pre-swizzled into B-fragment layout (prep kernel);
//    stage 3 reads it straight from global (L2/L3-resident, 192KB) -> the
//    12-chunk Wl staging loop and its 12 barriers are gone.
//  - cat lives in LDS as bf16 hi/lo [16][392] (padded stride, 16B-aligned
//    ds_read_b128 fragments). LDS 40KB -> 32KB; launch_bounds(256,5) -> 5
//    blocks/CU.
// Phases 1-2 + selection are untouched (bit-exact selection preserved).
// ---------------------------------------------------------------------------
__global__ __launch_bounds__(256, 5) void fused_kernel(
        const float4* __restrict__ xyz1n, const float* __restrict__ xyz2,
        const float* __restrict__ points1, const float* __restrict__ points2,
        const ushort* __restrict__ Wfh, const ushort* __restrict__ Wfl,
        const float* __restrict__ bias, float* __restrict__ out) {
    __shared__ __align__(16) char smem[32768];
    float4*   xyzt4 = (float4*)smem;                 // [0,16K)  phases 1-2
    uint64_t* wball = (uint64_t*)(smem + 16384);     // [16K,32K) phases 1-2
    ushort*   cat_h = (ushort*)smem;                 // [0,12544)   stages 2-3
    ushort*   cat_l = (ushort*)(smem + 12544);       // [12544,25088)

    const int tid   = threadIdx.x;
    const int lane  = tid & 63;
    const int w     = tid >> 6;
    const int qbase = blockIdx.x * 16 + w * 4;     // wave's 4 queries
    const int b     = (blockIdx.x * 16) >> 13;     // uniform per block

    float qx[4], qy[4], qz[4], s2[4];
    #pragma unroll
    for (int j = 0; j < 4; ++j) {
        const float* qp = xyz2 + (size_t)(qbase + j) * 3;
        qx[j] = qp[0]; qy[j] = qp[1]; qz[j] = qp[2];
        {
            #pragma clang fp contract(off)
            float px = qx[j] * qx[j], py = qy[j] * qy[j], pz = qz[j] * qz[j];
            s2[j] = (px + py) + pz;
        }
    }

    const float4* xb = xyz1n + (size_t)b * NQ;

    // ------- Phase 1: reduced-proxy lane-min scan over HALF the points -------
    float mn[4];
    #pragma unroll
    for (int j = 0; j < 4; ++j) mn[j] = __uint_as_float(0x7F800000u);

    for (int tile = 0; tile < 4; ++tile) {
        __syncthreads();
        {
            const float4* s4 = xb + tile * 1024;
            #pragma unroll
            for (int v = tid; v < 1024; v += 256) xyzt4[v] = s4[v];
        }
        __syncthreads();
        #pragma unroll 4
        for (int s = 0; s < 16; ++s) {
            float4 pt = xyzt4[s * 64 + lane];
            #pragma unroll
            for (int j = 0; j < 4; ++j)
                mn[j] = fminf(mn[j], red_r(pt, qx[j], qy[j], qz[j]));
        }
    }

    // 4 float bitonic sorts of lane minima; that[j] = s2 + rank15 + margin
    float that[4];
    #pragma unroll
    for (int j = 0; j < 4; ++j) {
        float x = mn[j];
        #pragma unroll
        for (int k = 2; k <= 64; k <<= 1) {
            #pragma unroll
            for (int jj = k >> 1; jj > 0; jj >>= 1) {
                float px = __shfl_xor(x, jj, 64);
                bool keep_min = (((lane & jj) == 0) == ((lane & k) == 0));
                float mnv = fminf(x, px), mxv = fmaxf(x, px);
                x = keep_min ? mnv : mxv;
            }
        }
        that[j] = s2[j] + __shfl(x, 15, 64) + RED_MARGIN;
    }

    // ------- Phase 2 (exact, branchless d2): gated compaction -------
    uint32_t cnt[4] = {0u, 0u, 0u, 0u};
    for (int tt = 0; tt < 8; ++tt) {
        const int tile = (3 + tt) & 7;             // tile 3 still resident
        if (tt > 0) {
            __syncthreads();
            const float4* s4 = xb + tile * 1024;
            #pragma unroll
            for (int v = tid; v < 1024; v += 256) xyzt4[v] = s4[v];
            __syncthreads();
        }
        const uint32_t base = (uint32_t)tile * 1024u;
        #pragma unroll 4
        for (int s = 0; s < 16; ++s) {
            float4 pt = xyzt4[s * 64 + lane];
            const uint32_t pidx = base + (uint32_t)(s * 64 + lane);
            #pragma unroll
            for (int j = 0; j < 4; ++j) {
                float d2 = npy_d2(pt, qx[j], qy[j], qz[j], s2[j]);
                bool  v  = (d2 <= that[j]);
                uint64_t mask = __ballot((int)v);
                if (mask != 0ull) {                // scalar gate
                    if (v) {
                        uint32_t below = __builtin_amdgcn_mbcnt_hi(
                            (uint32_t)(mask >> 32),
                            __builtin_amdgcn_mbcnt_lo((uint32_t)mask, 0u));
                        uint32_t pos    = cnt[j] + below;
                        uint32_t bits   = __float_as_uint(d2);
                        uint32_t mapped = bits ^ (0x80000000u |
                                          (uint32_t)((int32_t)bits >> 31));
                        if (pos < 128u)
                            wball[(w * 4 + j) * 128 + pos] =
                                ((uint64_t)mapped << 32) | (uint64_t)pidx;
                    }
                    cnt[j] += (uint32_t)__popcll(mask);
                }
            }
        }
    }

    // ---------------- per-query selection + weights (R8-exact) ----------------
    int   myidxA[4];
    float mywgtA[4];
    #pragma unroll
    for (int j = 0; j < 4; ++j) {
        const uint64_t* wb = wball + (size_t)(w * 4 + j) * 128;
        const uint32_t c = cnt[j];
        uint64_t mykey;
        if (c <= 64u) {                            // normal path
            uint64_t k0 = (lane < (int)c) ? wb[lane] : ~0ull;
            mykey = sort64(k0, lane);
        } else {                                   // uniform fallback
            uint32_t cc = c > 128u ? 128u : c;
            uint64_t k0 = wb[lane];
            uint64_t k1 = (lane + 64 < (int)cc) ? wb[lane + 64] : ~0ull;
            k0 = sort64(k0, lane);
            k1 = sort64(k1, lane);
            uint64_t t1 = __shfl((unsigned long long)k1, lane & 15, 64);
            uint64_t km = (lane < 16) ? k0 : ((lane < 32) ? t1 : ~0ull);
            mykey = sort64(km, lane);
        }
        uint32_t mhi   = (uint32_t)(mykey >> 32);
        uint32_t rbits = (mhi & 0x80000000u) ? (mhi ^ 0x80000000u) : ~mhi;
        float    d2w   = __uint_as_float(rbits);
        myidxA[j] = (int)(uint32_t)(mykey & 0xFFFFFFFFull);
        float recip = (lane < KQ) ? (1.0f / (d2w + 1e-8f)) : 0.0f;
        float tot = recip;
        #pragma unroll
        for (int sh = 1; sh < 16; sh <<= 1) tot += __shfl_xor(tot, sh, 64);
        mywgtA[j] = recip / tot;                   // valid in lanes 0..15
    }

    // LDS reuse boundary: all waves done with xyzt4 + wball
    __syncthreads();

    // ------- Stage 2: build cat (bf16 hi/lo split) [16][392] in LDS -------
    const float* p2b = points2 + (size_t)b * NQ * D2Q;
    #pragma unroll
    for (int j = 0; j < 4; ++j) {
        const int qi = w * 4 + j;
        // p1 part: 128 floats, lanes 0..31
        if (lane < 32) {
            float4 p = ((const float4*)(points1 + (size_t)(qbase + j) * D1Q))[lane];
            ushort4 hv, lv;
            hv.x = f2bf(p.x); lv.x = f2bf(p.x - bf2f(hv.x));
            hv.y = f2bf(p.y); lv.y = f2bf(p.y - bf2f(hv.y));
            hv.z = f2bf(p.z); lv.z = f2bf(p.z - bf2f(hv.z));
            hv.w = f2bf(p.w); lv.w = f2bf(p.w - bf2f(hv.w));
            *(ushort4*)&cat_h[qi * 392 + lane * 4] = hv;
            *(ushort4*)&cat_l[qi * 392 + lane * 4] = lv;
        }
        // interp part: 256 floats, all 64 lanes; k ascending (reference order)
        float4 acc = make_float4(0.f, 0.f, 0.f, 0.f);
        #pragma unroll
        for (int k = 0; k < KQ; ++k) {
            int   kk = __builtin_amdgcn_readlane(myidxA[j], k);
            float wk = __uint_as_float((uint32_t)__builtin_amdgcn_readlane(
                           (int)__float_as_uint(mywgtA[j]), k));
            float4 row = ((const float4*)(p2b + (size_t)kk * D2Q))[lane];
            acc.x = fmaf(wk, row.x, acc.x);
            acc.y = fmaf(wk, row.y, acc.y);
            acc.z = fmaf(wk, row.z, acc.z);
            acc.w = fmaf(wk, row.w, acc.w);
        }
        {
            ushort4 hv, lv;
            hv.x = f2bf(acc.x); lv.x = f2bf(acc.x - bf2f(hv.x));
            hv.y = f2bf(acc.y); lv.y = f2bf(acc.y - bf2f(hv.y));
            hv.z = f2bf(acc.z); lv.z = f2bf(acc.z - bf2f(hv.z));
            hv.w = f2bf(acc.w); lv.w = f2bf(acc.w - bf2f(hv.w));
            *(ushort4*)&cat_h[qi * 392 + D1Q + lane * 4] = hv;
            *(ushort4*)&cat_l[qi * 392 + D1Q + lane * 4] = lv;
        }
    }
    __syncthreads();

    // ------- Stage 3: MFMA GEMM  C[16][128] = cat[16][384] @ Wt[384][128] -------
    // Wave w owns col-tiles {2w, 2w+1}. 12 k-steps of K=32, 3-term bf16 split.
    {
        const int arow = lane & 15;
        const int koff = (lane >> 4) * 8;
        const int ct0  = w * 2;
        f32x4v acc0 = {0.f, 0.f, 0.f, 0.f};
        f32x4v acc1 = {0.f, 0.f, 0.f, 0.f};
        #pragma unroll 4
        for (int kt = 0; kt < 12; ++kt) {
            short8v ah = *(const short8v*)&cat_h[arow * 392 + kt * 32 + koff];
            short8v al = *(const short8v*)&cat_l[arow * 392 + kt * 32 + koff];
            const ushort* bhp = Wfh + ((size_t)(kt * 8 + ct0) * 64 + lane) * 8;
            const ushort* blp = Wfl + ((size_t)(kt * 8 + ct0) * 64 + lane) * 8;
            short8v bh0 = *(const short8v*)bhp;
            short8v bl0 = *(const short8v*)blp;
            short8v bh1 = *(const short8v*)(bhp + 512);
            short8v bl1 = *(const short8v*)(blp + 512);
            acc0 = __builtin_amdgcn_mfma_f32_16x16x32_bf16(ah, bh0, acc0, 0, 0, 0);
            acc0 = __builtin_amdgcn_mfma_f32_16x16x32_bf16(al, bh0, acc0, 0, 0, 0);
            acc0 = __builtin_amdgcn_mfma_f32_16x16x32_bf16(ah, bl0, acc0, 0, 0, 0);
            acc1 = __builtin_amdgcn_mfma_f32_16x16x32_bf16(ah, bh1, acc1, 0, 0, 0);
            acc1 = __builtin_amdgcn_mfma_f32_16x16x32_bf16(al, bh1, acc1, 0, 0, 0);
            acc1 = __builtin_amdgcn_mfma_f32_16x16x32_bf16(ah, bl1, acc1, 0, 0, 0);
        }
        // C/D layout: col = lane&15, row = (lane>>4)*4 + r  (m89-verified)
        const int col0 = ct0 * 16 + (lane & 15);
        const int row0 = blockIdx.x * 16 + (lane >> 4) * 4;
        const float bv0 = bias[col0];
        const float bv1 = bias[col0 + 16];
        #pragma unroll
        for (int r = 0; r < 4; ++r) {
            out[(size_t)(row0 + r) * OUTQ + col0]      = acc0[r] + bv0;
            out[(size_t)(row0 + r) * OUTQ + col0 + 16] = acc1[r] + bv1;
        }
    }
}

// ---------------------------------------------------------------------------
// Launch
// ---------------------------------------------------------------------------
extern "C" void kernel_launch(void* const* d_in, const int* in_sizes, int n_in,
                              void* d_out, int out_size, void* d_ws, size_t ws_size,
                              hipStream_t stream) {
    const float* xyz1    = (const float*)d_in[0];
    const float* xyz2    = (const float*)d_in[1];
    const float* points1 = (const float*)d_in[2];
    const float* points2 = (const float*)d_in[3];
    const float* W       = (const float*)d_in[4];
    const float* bias    = (const float*)d_in[5];

    // ws layout (bytes): [0,98304) Wfh  [98304,196608) Wfl  [196608,458752) xyz1n
    ushort* Wfh   = (ushort*)d_ws;
    ushort* Wfl   = (ushort*)((char*)d_ws + 98304);
    float4* xyz1n = (float4*)((char*)d_ws + 196608);

    prep_kernel<<<192, 256, 0, stream>>>(W, Wfh, Wfl, xyz1, xyz1n);
    fused_kernel<<<(BQ * NQ) / 16, 256, 0, stream>>>(
        xyz1n, xyz2, points1, points2, Wfh, Wfl, bias, (float*)d_out);
}